// Round 1
// baseline (1407.090 us; speedup 1.0000x reference)
//
#include <hip/hip_runtime.h>

#define N_NODES 100000
#define D 64

// Wave-per-edge scatter: lane d accumulates feature d of x[src] into agg[dst].
__global__ void scatter_deg_kernel(const float* __restrict__ feat,
                                   const int* __restrict__ src,
                                   const int* __restrict__ dst,
                                   float* __restrict__ agg,
                                   float* __restrict__ deg,
                                   int nEdges, int doDeg) {
  int gtid = blockIdx.x * blockDim.x + threadIdx.x;
  int wave = gtid >> 6;
  int lane = threadIdx.x & 63;
  int nWaves = (gridDim.x * blockDim.x) >> 6;
  for (int e = wave; e < nEdges; e += nWaves) {
    int s = src[e];
    int d = dst[e];
    float v = feat[(size_t)s * D + lane];
    atomicAdd(&agg[(size_t)d * D + lane], v);
    if (doDeg && lane == 0) atomicAdd(&deg[d], 1.0f);
  }
}

// Fused: mean = agg/max(deg,1); h = [relu](mean @ Wl^T + bl + x @ Wr^T)
// Block = 256 threads = 4 nodes x 64 output features. W staged transposed in
// LDS so lane j reads WT[k*64+j] (consecutive -> conflict-free); per-node
// mean/x rows are wave-uniform broadcasts (1 node per wave).
__global__ __launch_bounds__(256) void sage_layer1_kernel(
    const float* __restrict__ agg, const float* __restrict__ deg,
    const float* __restrict__ xin,
    const float* __restrict__ Wl, const float* __restrict__ bl,
    const float* __restrict__ Wr,
    float* __restrict__ hout) {
  __shared__ float WlT[D * D];
  __shared__ float WrT[D * D];
  __shared__ float mS[4][D];
  __shared__ float xS[4][D];
  int tid = threadIdx.x;
  for (int i = tid; i < D * D; i += 256) {
    int j = i >> 6, k = i & 63;
    WlT[k * D + j] = Wl[i];
    WrT[k * D + j] = Wr[i];
  }
  int j = tid & 63, ln = tid >> 6;
  int n = blockIdx.x * 4 + ln;  // N_NODES % 4 == 0 -> always in range
  float dg = fmaxf(deg[n], 1.0f);
  mS[ln][j] = agg[(size_t)n * D + j] / dg;
  xS[ln][j] = xin[(size_t)n * D + j];
  __syncthreads();
  float acc = bl[j];
#pragma unroll
  for (int k = 0; k < D; ++k)
    acc = fmaf(mS[ln][k], WlT[k * D + j], fmaf(xS[ln][k], WrT[k * D + j], acc));
  acc = fmaxf(acc, 0.0f);  // relu
  hout[(size_t)n * D + j] = acc;
}

// Layer 2 (no relu) + fused classifier (64 -> 2) to avoid materializing h2.
__global__ __launch_bounds__(256) void sage_layer2_cls_kernel(
    const float* __restrict__ agg, const float* __restrict__ deg,
    const float* __restrict__ h1,
    const float* __restrict__ Wl, const float* __restrict__ bl,
    const float* __restrict__ Wr,
    const float* __restrict__ Wc, const float* __restrict__ bc,
    float* __restrict__ out) {
  __shared__ float WlT[D * D];
  __shared__ float WrT[D * D];
  __shared__ float mS[4][D];
  __shared__ float xS[4][D];
  __shared__ float h2S[4][D];
  int tid = threadIdx.x;
  for (int i = tid; i < D * D; i += 256) {
    int j = i >> 6, k = i & 63;
    WlT[k * D + j] = Wl[i];
    WrT[k * D + j] = Wr[i];
  }
  int j = tid & 63, ln = tid >> 6;
  int n = blockIdx.x * 4 + ln;
  float dg = fmaxf(deg[n], 1.0f);
  mS[ln][j] = agg[(size_t)n * D + j] / dg;
  xS[ln][j] = h1[(size_t)n * D + j];
  __syncthreads();
  float acc = bl[j];
#pragma unroll
  for (int k = 0; k < D; ++k)
    acc = fmaf(mS[ln][k], WlT[k * D + j], fmaf(xS[ln][k], WrT[k * D + j], acc));
  h2S[ln][j] = acc;
  __syncthreads();
  // classifier: 8 threads (4 nodes x 2 classes)
  if (tid < 8) {
    int l2 = tid >> 1, c = tid & 1;
    int nn = blockIdx.x * 4 + l2;
    float a = bc[c];
#pragma unroll
    for (int k = 0; k < D; ++k) a = fmaf(h2S[l2][k], Wc[c * D + k], a);
    out[(size_t)nn * 2 + c] = a;
  }
}

extern "C" void kernel_launch(void* const* d_in, const int* in_sizes, int n_in,
                              void* d_out, int out_size, void* d_ws,
                              size_t ws_size, hipStream_t stream) {
  const float* x   = (const float*)d_in[0];
  const int*   ei  = (const int*)d_in[1];
  const float* Wl1 = (const float*)d_in[2];
  const float* bl1 = (const float*)d_in[3];
  const float* Wr1 = (const float*)d_in[4];
  const float* Wl2 = (const float*)d_in[5];
  const float* bl2 = (const float*)d_in[6];
  const float* Wr2 = (const float*)d_in[7];
  const float* Wc  = (const float*)d_in[8];
  const float* bc  = (const float*)d_in[9];
  float* out = (float*)d_out;

  int nEdges = in_sizes[1] / 2;
  const int* src = ei;
  const int* dst = ei + nEdges;

  // Workspace: agg [N*64] | h1 [N*64] | deg [N]
  float* agg = (float*)d_ws;
  float* h1  = agg + (size_t)N_NODES * D;
  float* deg = h1 + (size_t)N_NODES * D;

  hipMemsetAsync(agg, 0, (size_t)N_NODES * D * sizeof(float), stream);
  hipMemsetAsync(deg, 0, (size_t)N_NODES * sizeof(float), stream);

  dim3 blk(256);
  const int scatterBlocks = 8192;

  // Layer 1
  scatter_deg_kernel<<<scatterBlocks, blk, 0, stream>>>(x, src, dst, agg, deg,
                                                        nEdges, 1);
  sage_layer1_kernel<<<N_NODES / 4, blk, 0, stream>>>(agg, deg, x, Wl1, bl1,
                                                      Wr1, h1);

  // Layer 2 (deg unchanged -- reuse)
  hipMemsetAsync(agg, 0, (size_t)N_NODES * D * sizeof(float), stream);
  scatter_deg_kernel<<<scatterBlocks, blk, 0, stream>>>(h1, src, dst, agg, deg,
                                                        nEdges, 0);
  sage_layer2_cls_kernel<<<N_NODES / 4, blk, 0, stream>>>(agg, deg, h1, Wl2,
                                                          bl2, Wr2, Wc, bc,
                                                          out);
}

// Round 2
// 590.317 us; speedup vs baseline: 2.3836x; 2.3836x over previous
//
#include <hip/hip_runtime.h>

#define N_NODES 100000
#define D 64
#define WPAD 65          // padded leading dim: write addr k*65+j -> bank k%32, conflict-free
#define NPB 8            // nodes per block (2 per wave)
#define SCAN_CHUNK 256
#define NBLK_SCAN ((N_NODES + SCAN_CHUNK - 1) / SCAN_CHUNK)  // 391

// ---------- CSR build ----------

__global__ void hist_kernel(const int* __restrict__ dst, int* __restrict__ degI,
                            int nE) {
  int i = blockIdx.x * blockDim.x + threadIdx.x;
  int stride = gridDim.x * blockDim.x;
  for (int e = i; e < nE; e += stride) atomicAdd(&degI[dst[e]], 1);
}

__global__ void scan_p1(const int* __restrict__ degI, int* __restrict__ bsum) {
  int t = threadIdx.x, b = blockIdx.x;
  int i = b * SCAN_CHUNK + t;
  int v = (i < N_NODES) ? degI[i] : 0;
  for (int off = 32; off; off >>= 1) v += __shfl_down(v, off);
  __shared__ int ws4[4];
  if ((t & 63) == 0) ws4[t >> 6] = v;
  __syncthreads();
  if (t == 0) bsum[b] = ws4[0] + ws4[1] + ws4[2] + ws4[3];
}

__global__ void scan_p2(int* __restrict__ bsum, int nB) {
  __shared__ int s[512];
  int t = threadIdx.x;
  int orig = (t < nB) ? bsum[t] : 0;
  s[t] = orig;
  __syncthreads();
  for (int off = 1; off < 512; off <<= 1) {
    int v = (t >= off) ? s[t - off] : 0;
    __syncthreads();
    s[t] += v;
    __syncthreads();
  }
  if (t < nB) bsum[t] = s[t] - orig;  // exclusive block offsets
}

__global__ void scan_p3(const int* __restrict__ degI, const int* __restrict__ bsum,
                        int* __restrict__ rowstart, int* __restrict__ cursor) {
  __shared__ int s[SCAN_CHUNK];
  int t = threadIdx.x, b = blockIdx.x;
  int i = b * SCAN_CHUNK + t;
  int d = (i < N_NODES) ? degI[i] : 0;
  s[t] = d;
  __syncthreads();
  for (int off = 1; off < SCAN_CHUNK; off <<= 1) {
    int v = (t >= off) ? s[t - off] : 0;
    __syncthreads();
    s[t] += v;
    __syncthreads();
  }
  if (i < N_NODES) {
    int ex = s[t] - d + bsum[b];
    rowstart[i] = ex;
    cursor[i] = ex;
  }
}

__global__ void build_adj_kernel(const int* __restrict__ src,
                                 const int* __restrict__ dst,
                                 int* __restrict__ cursor, int* __restrict__ adj,
                                 int nE) {
  int i = blockIdx.x * blockDim.x + threadIdx.x;
  int stride = gridDim.x * blockDim.x;
  for (int e = i; e < nE; e += stride) {
    int d = dst[e];
    int p = atomicAdd(&cursor[d], 1);
    adj[p] = src[e];
  }
}

// ---------- Fused SAGE layer: CSR mean-gather + dual GEMV (+relu / +classifier)
// Block = 256 threads = 4 waves; one node per wave per iteration (NPB/4 iters).
// W staged transposed+padded in LDS (conflict-free both on store and load).

__global__ __launch_bounds__(256) void sage_fused_kernel(
    const int* __restrict__ rowstart, const int* __restrict__ degI,
    const int* __restrict__ adj, const float* __restrict__ feat,
    const float* __restrict__ Wl, const float* __restrict__ bl,
    const float* __restrict__ Wr, const float* __restrict__ Wc,
    const float* __restrict__ bc, float* __restrict__ outp, int mode) {
  __shared__ float WlT[D * WPAD];
  __shared__ float WrT[D * WPAD];
  __shared__ float mS[4][D];
  __shared__ float xS[4][D];
  int tid = threadIdx.x;
  for (int i = tid; i < D * D; i += 256) {
    int j = i >> 6, k = i & 63;
    WlT[k * WPAD + j] = Wl[i];
    WrT[k * WPAD + j] = Wr[i];
  }
  __syncthreads();
  int lane = tid & 63, w = tid >> 6;
  for (int ni = 0; ni < NPB / 4; ++ni) {
    int n = blockIdx.x * NPB + ni * 4 + w;  // N_NODES % NPB == 0
    int rs = rowstart[n];
    int dg = degI[n];
    float s = 0.f;
    for (int base = 0; base < dg; base += 64) {
      int cnt = min(64, dg - base);
      int a = (lane < cnt) ? adj[rs + base + lane] : 0;
      for (int ii = 0; ii < cnt; ++ii) {
        int nb = __shfl(a, ii);
        s += feat[(size_t)nb * D + lane];
      }
    }
    float mean = s / (float)max(dg, 1);
    float xv = feat[(size_t)n * D + lane];
    mS[w][lane] = mean;
    xS[w][lane] = xv;
    __syncthreads();
    float acc = bl[lane];
#pragma unroll
    for (int k = 0; k < D; ++k)
      acc = fmaf(mS[w][k], WlT[k * WPAD + lane],
                 fmaf(xS[w][k], WrT[k * WPAD + lane], acc));
    if (mode == 0) {
      outp[(size_t)n * D + lane] = fmaxf(acc, 0.f);
    } else {
      // fused classifier: out[n][c] = sum_j h2[j]*Wc[c][j] + bc[c]
      float v0 = acc * Wc[lane];
      float v1 = acc * Wc[D + lane];
      for (int off = 32; off; off >>= 1) {
        v0 += __shfl_down(v0, off);
        v1 += __shfl_down(v1, off);
      }
      if (lane == 0) {
        outp[(size_t)n * 2 + 0] = v0 + bc[0];
        outp[(size_t)n * 2 + 1] = v1 + bc[1];
      }
    }
    __syncthreads();  // mS/xS reused next iteration
  }
}

extern "C" void kernel_launch(void* const* d_in, const int* in_sizes, int n_in,
                              void* d_out, int out_size, void* d_ws,
                              size_t ws_size, hipStream_t stream) {
  const float* x   = (const float*)d_in[0];
  const int*   ei  = (const int*)d_in[1];
  const float* Wl1 = (const float*)d_in[2];
  const float* bl1 = (const float*)d_in[3];
  const float* Wr1 = (const float*)d_in[4];
  const float* Wl2 = (const float*)d_in[5];
  const float* bl2 = (const float*)d_in[6];
  const float* Wr2 = (const float*)d_in[7];
  const float* Wc  = (const float*)d_in[8];
  const float* bc  = (const float*)d_in[9];
  float* out = (float*)d_out;

  int nE = in_sizes[1] / 2;
  const int* src = ei;
  const int* dst = ei + nE;

  // Workspace: h1 [N*64] f32 | degI [N] | rowstart [N] | cursor [N] | bsum [512] | adj [E]
  float* h1 = (float*)d_ws;
  int* degI = (int*)(h1 + (size_t)N_NODES * D);
  int* rowstart = degI + N_NODES;
  int* cursor = rowstart + N_NODES;
  int* bsum = cursor + N_NODES;
  int* adj = bsum + 512;

  hipMemsetAsync(degI, 0, N_NODES * sizeof(int), stream);

  dim3 blk(256);
  hist_kernel<<<2048, blk, 0, stream>>>(dst, degI, nE);
  scan_p1<<<NBLK_SCAN, blk, 0, stream>>>(degI, bsum);
  scan_p2<<<1, 512, 0, stream>>>(bsum, NBLK_SCAN);
  scan_p3<<<NBLK_SCAN, blk, 0, stream>>>(degI, bsum, rowstart, cursor);
  build_adj_kernel<<<2048, blk, 0, stream>>>(src, dst, cursor, adj, nE);

  // Layer 1: feat=x -> h1 (relu)
  sage_fused_kernel<<<N_NODES / NPB, blk, 0, stream>>>(
      rowstart, degI, adj, x, Wl1, bl1, Wr1, Wc, bc, h1, 0);
  // Layer 2: feat=h1 -> out (fused classifier)
  sage_fused_kernel<<<N_NODES / NPB, blk, 0, stream>>>(
      rowstart, degI, adj, h1, Wl2, bl2, Wr2, Wc, bc, out, 1);
}

// Round 3
// 409.272 us; speedup vs baseline: 3.4380x; 1.4424x over previous
//
#include <hip/hip_runtime.h>

#define N_NODES 100000
#define D 64
#define ROWP 17  // float4 per padded WT row (272B rows, 16B aligned)
#define SCAN_CHUNK 256
#define NBLK_SCAN ((N_NODES + SCAN_CHUNK - 1) / SCAN_CHUNK)  // 391

// ---------- CSR build ----------

__global__ void hist_kernel(const int* __restrict__ dst, int* __restrict__ degI,
                            int nE) {
  int i = blockIdx.x * blockDim.x + threadIdx.x;
  int stride = gridDim.x * blockDim.x;
  for (int e = i; e < nE; e += stride) atomicAdd(&degI[dst[e]], 1);
}

__global__ void scan_p1(const int* __restrict__ degI, int* __restrict__ bsum) {
  int t = threadIdx.x, b = blockIdx.x;
  int i = b * SCAN_CHUNK + t;
  int v = (i < N_NODES) ? degI[i] : 0;
  for (int off = 32; off; off >>= 1) v += __shfl_down(v, off);
  __shared__ int ws4[4];
  if ((t & 63) == 0) ws4[t >> 6] = v;
  __syncthreads();
  if (t == 0) bsum[b] = ws4[0] + ws4[1] + ws4[2] + ws4[3];
}

__global__ void scan_p2(int* __restrict__ bsum, int nB) {
  __shared__ int s[512];
  int t = threadIdx.x;
  int orig = (t < nB) ? bsum[t] : 0;
  s[t] = orig;
  __syncthreads();
  for (int off = 1; off < 512; off <<= 1) {
    int v = (t >= off) ? s[t - off] : 0;
    __syncthreads();
    s[t] += v;
    __syncthreads();
  }
  if (t < nB) bsum[t] = s[t] - orig;  // exclusive block offsets
}

__global__ void scan_p3(const int* __restrict__ degI, const int* __restrict__ bsum,
                        int* __restrict__ rowstart, int* __restrict__ cursor) {
  __shared__ int s[SCAN_CHUNK];
  int t = threadIdx.x, b = blockIdx.x;
  int i = b * SCAN_CHUNK + t;
  int d = (i < N_NODES) ? degI[i] : 0;
  s[t] = d;
  __syncthreads();
  for (int off = 1; off < SCAN_CHUNK; off <<= 1) {
    int v = (t >= off) ? s[t - off] : 0;
    __syncthreads();
    s[t] += v;
    __syncthreads();
  }
  if (i < N_NODES) {
    int ex = s[t] - d + bsum[b];
    rowstart[i] = ex;
    cursor[i] = ex;
  }
}

__global__ void build_adj_kernel(const int* __restrict__ src,
                                 const int* __restrict__ dst,
                                 int* __restrict__ cursor, int* __restrict__ adj,
                                 int nE) {
  int i = blockIdx.x * blockDim.x + threadIdx.x;
  int stride = gridDim.x * blockDim.x;
  for (int e = i; e < nE; e += stride) {
    int d = dst[e];
    int p = atomicAdd(&cursor[d], 1);
    adj[p] = src[e];
  }
}

// ---------- Fused SAGE layer v2 ----------
// Wave-per-node, no intra-node-loop barriers. Gather: quarter-wave per edge,
// float4 rows, 4 iterations (16 edges) of loads in flight. GEMV: lane (q,j4)
// owns outputs 4j4..4j4+3 over k in [16q,16q+16); W transposed in LDS with
// row-slot permute slot=(k>>4)+4*(k&15) so quarters read different banks;
// m[k]/x[k] broadcast via in-register shfl (static component selection).

__global__ __launch_bounds__(512) void sage_fused_v2(
    const int* __restrict__ rowstart, const int* __restrict__ degI,
    const int* __restrict__ adj, const float* __restrict__ feat,
    const float* __restrict__ Wl, const float* __restrict__ bl,
    const float* __restrict__ Wr, const float* __restrict__ Wc,
    const float* __restrict__ bc, float* __restrict__ outp,
    int nE, int mode) {
  __shared__ float4 WlT4[64 * ROWP];
  __shared__ float4 WrT4[64 * ROWP];
  const float4* feat4 = (const float4*)feat;
  int tid = threadIdx.x;
  // Stage W transposed: WT[k][j] = W[j][k], stored as float4 over j, row slot
  // permuted. Source reads are strided but L1-resident (16KB matrices).
  for (int i = tid; i < 1024; i += 512) {
    int k = i >> 4, j4s = i & 15;
    int slot = (k >> 4) + (k & 15) * 4;
    float4 wa, wb;
    wa.x = Wl[(4 * j4s + 0) * D + k];
    wa.y = Wl[(4 * j4s + 1) * D + k];
    wa.z = Wl[(4 * j4s + 2) * D + k];
    wa.w = Wl[(4 * j4s + 3) * D + k];
    wb.x = Wr[(4 * j4s + 0) * D + k];
    wb.y = Wr[(4 * j4s + 1) * D + k];
    wb.z = Wr[(4 * j4s + 2) * D + k];
    wb.w = Wr[(4 * j4s + 3) * D + k];
    WlT4[slot * ROWP + j4s] = wa;
    WrT4[slot * ROWP + j4s] = wb;
  }
  __syncthreads();

  int lane = tid & 63;
  int q = lane >> 4, j4 = lane & 15;
  float4 blr = ((const float4*)bl)[j4];
  float4 wc0 = ((const float4*)Wc)[j4];
  float4 wc1 = ((const float4*)Wc)[16 + j4];
  float bc0 = bc[0], bc1 = bc[1];

  int nWaves = (gridDim.x * blockDim.x) >> 6;
  int gw = (blockIdx.x * blockDim.x + tid) >> 6;

  for (int n = gw; n < N_NODES; n += nWaves) {
    int rs = rowstart[n];
    int dg = degI[n];
    // own features (16 distinct float4, 4-way broadcast -> one 256B fetch)
    float4 xv = feat4[(size_t)n * 16 + j4];
    float4 acc = make_float4(0.f, 0.f, 0.f, 0.f);
    for (int base = 0; base < dg; base += 64) {
      int cnt = min(dg - base, 64);
      int aidx = rs + base + lane;
      int a = adj[min(aidx, nE - 1)];
      int nIter = (cnt + 3) >> 2;
      for (int t0 = 0; t0 < nIter; t0 += 4) {
        float4 v0, v1, v2, v3;
        float m0, m1, m2, m3;
        int el, nb;
        bool ok;
        el = (t0 + 0) * 4 + q; ok = el < cnt;
        nb = __shfl(a, el < 64 ? el : 0); nb = ok ? nb : n;
        v0 = feat4[(size_t)nb * 16 + j4]; m0 = ok ? 1.f : 0.f;
        el = (t0 + 1) * 4 + q; ok = el < cnt;
        nb = __shfl(a, el < 64 ? el : 0); nb = ok ? nb : n;
        v1 = feat4[(size_t)nb * 16 + j4]; m1 = ok ? 1.f : 0.f;
        el = (t0 + 2) * 4 + q; ok = el < cnt;
        nb = __shfl(a, el < 64 ? el : 0); nb = ok ? nb : n;
        v2 = feat4[(size_t)nb * 16 + j4]; m2 = ok ? 1.f : 0.f;
        el = (t0 + 3) * 4 + q; ok = el < cnt;
        nb = __shfl(a, el < 64 ? el : 0); nb = ok ? nb : n;
        v3 = feat4[(size_t)nb * 16 + j4]; m3 = ok ? 1.f : 0.f;
        acc.x = fmaf(v0.x, m0, acc.x); acc.y = fmaf(v0.y, m0, acc.y);
        acc.z = fmaf(v0.z, m0, acc.z); acc.w = fmaf(v0.w, m0, acc.w);
        acc.x = fmaf(v1.x, m1, acc.x); acc.y = fmaf(v1.y, m1, acc.y);
        acc.z = fmaf(v1.z, m1, acc.z); acc.w = fmaf(v1.w, m1, acc.w);
        acc.x = fmaf(v2.x, m2, acc.x); acc.y = fmaf(v2.y, m2, acc.y);
        acc.z = fmaf(v2.z, m2, acc.z); acc.w = fmaf(v2.w, m2, acc.w);
        acc.x = fmaf(v3.x, m3, acc.x); acc.y = fmaf(v3.y, m3, acc.y);
        acc.z = fmaf(v3.z, m3, acc.z); acc.w = fmaf(v3.w, m3, acc.w);
      }
    }
    // cross-quarter reduce: every lane ends with full sums for its 4 features
    acc.x += __shfl_xor(acc.x, 16); acc.x += __shfl_xor(acc.x, 32);
    acc.y += __shfl_xor(acc.y, 16); acc.y += __shfl_xor(acc.y, 32);
    acc.z += __shfl_xor(acc.z, 16); acc.z += __shfl_xor(acc.z, 32);
    acc.w += __shfl_xor(acc.w, 16); acc.w += __shfl_xor(acc.w, 32);
    float inv = 1.f / (float)max(dg, 1);
    float4 mean = make_float4(acc.x * inv, acc.y * inv, acc.z * inv, acc.w * inv);

    // dual GEMV: k = q*16 + kg*4 + kc
    float4 o = make_float4(0.f, 0.f, 0.f, 0.f);
#pragma unroll
    for (int kg = 0; kg < 4; ++kg) {
#pragma unroll
      for (int kc = 0; kc < 4; ++kc) {
        int slot = q + 16 * kg + 4 * kc;  // = (k>>4) + 4*(k&15)
        float4 wl4 = WlT4[slot * ROWP + j4];
        float4 wr4 = WrT4[slot * ROWP + j4];
        int srcl = q * 4 + kg;  // lane holding m[k]/x[k]
        float mc = (kc == 0) ? mean.x : (kc == 1) ? mean.y : (kc == 2) ? mean.z : mean.w;
        float xc = (kc == 0) ? xv.x : (kc == 1) ? xv.y : (kc == 2) ? xv.z : xv.w;
        float mkv = __shfl(mc, srcl);
        float xkv = __shfl(xc, srcl);
        o.x = fmaf(mkv, wl4.x, fmaf(xkv, wr4.x, o.x));
        o.y = fmaf(mkv, wl4.y, fmaf(xkv, wr4.y, o.y));
        o.z = fmaf(mkv, wl4.z, fmaf(xkv, wr4.z, o.z));
        o.w = fmaf(mkv, wl4.w, fmaf(xkv, wr4.w, o.w));
      }
    }
    // reduce partial k-ranges across quarters
    o.x += __shfl_xor(o.x, 16); o.x += __shfl_xor(o.x, 32);
    o.y += __shfl_xor(o.y, 16); o.y += __shfl_xor(o.y, 32);
    o.z += __shfl_xor(o.z, 16); o.z += __shfl_xor(o.z, 32);
    o.w += __shfl_xor(o.w, 16); o.w += __shfl_xor(o.w, 32);
    o.x += blr.x; o.y += blr.y; o.z += blr.z; o.w += blr.w;

    if (mode == 0) {
      o.x = fmaxf(o.x, 0.f); o.y = fmaxf(o.y, 0.f);
      o.z = fmaxf(o.z, 0.f); o.w = fmaxf(o.w, 0.f);
      if (lane < 16) ((float4*)outp)[(size_t)n * 16 + lane] = o;
    } else {
      float4 wc = (q & 1) ? wc1 : wc0;
      float p = o.x * wc.x + o.y * wc.y + o.z * wc.z + o.w * wc.w;
      p += __shfl_xor(p, 1); p += __shfl_xor(p, 2);
      p += __shfl_xor(p, 4); p += __shfl_xor(p, 8);
      if (lane == 0) outp[(size_t)n * 2 + 0] = p + bc0;
      if (lane == 16) outp[(size_t)n * 2 + 1] = p + bc1;
    }
  }
}

extern "C" void kernel_launch(void* const* d_in, const int* in_sizes, int n_in,
                              void* d_out, int out_size, void* d_ws,
                              size_t ws_size, hipStream_t stream) {
  const float* x   = (const float*)d_in[0];
  const int*   ei  = (const int*)d_in[1];
  const float* Wl1 = (const float*)d_in[2];
  const float* bl1 = (const float*)d_in[3];
  const float* Wr1 = (const float*)d_in[4];
  const float* Wl2 = (const float*)d_in[5];
  const float* bl2 = (const float*)d_in[6];
  const float* Wr2 = (const float*)d_in[7];
  const float* Wc  = (const float*)d_in[8];
  const float* bc  = (const float*)d_in[9];
  float* out = (float*)d_out;

  int nE = in_sizes[1] / 2;
  const int* src = ei;
  const int* dst = ei + nE;

  // Workspace: h1 [N*64] f32 | degI [N] | rowstart [N] | cursor [N] | bsum [512] | adj [E]
  float* h1 = (float*)d_ws;
  int* degI = (int*)(h1 + (size_t)N_NODES * D);
  int* rowstart = degI + N_NODES;
  int* cursor = rowstart + N_NODES;
  int* bsum = cursor + N_NODES;
  int* adj = bsum + 512;

  hipMemsetAsync(degI, 0, N_NODES * sizeof(int), stream);

  dim3 blk(256);
  hist_kernel<<<2048, blk, 0, stream>>>(dst, degI, nE);
  scan_p1<<<NBLK_SCAN, blk, 0, stream>>>(degI, bsum);
  scan_p2<<<1, 512, 0, stream>>>(bsum, NBLK_SCAN);
  scan_p3<<<NBLK_SCAN, blk, 0, stream>>>(degI, bsum, rowstart, cursor);
  build_adj_kernel<<<2048, blk, 0, stream>>>(src, dst, cursor, adj, nE);

  // Layer 1: feat=x -> h1 (relu). Layer 2: feat=h1 -> out (classifier).
  sage_fused_v2<<<1024, 512, 0, stream>>>(rowstart, degI, adj, x, Wl1, bl1,
                                          Wr1, Wc, bc, h1, nE, 0);
  sage_fused_v2<<<1024, 512, 0, stream>>>(rowstart, degI, adj, h1, Wl2, bl2,
                                          Wr2, Wc, bc, out, nE, 1);
}